// Round 14
// baseline (980.203 us; speedup 1.0000x reference)
//
#include <hip/hip_runtime.h>
#include <math.h>

#define BB 64
#define TT 2048
#define ADIM 384
#define NE 10    // num_embeddings == LSTM hidden
#define NG 40    // 4*NE gates
#define HD 3     // hidden_dim (codebook width)

// ---------------- workspace layout (bytes) ----------------
#define OFF_X32   0ULL                        // BB*TT*NG*4 = 20971520 (+slack)
#define OFF_H     (41943040ULL + 126400ULL)   // BB*TT*NE*4 = 5242880
#define OFF_IDX   (OFF_H + 5242880ULL)        // BB*TT*4 = 524288
#define OFF_PART  (OFF_IDX + 524288ULL)       // 64*8 partials
#define OFF_DUMP  (OFF_PART + 4096ULL)        // per-block dump words (64*256B)

// ---------------- fast helpers ----------------
__device__ __forceinline__ float fexp2(float x) {   // HW 2^x, ~1 ulp
    float r;
    asm("v_exp_f32 %0, %1" : "=v"(r) : "v"(x));
    return r;
}
__device__ __forceinline__ float frcp(float d) {    // HW rcp, ~1 ulp
    float r;
    asm("v_rcp_f32 %0, %1" : "=v"(r) : "v"(d));
    return r;
}

template<int CTRL>
__device__ __forceinline__ float dpp_mov_f32(float x) {
    int v = __float_as_int(x);
    v = __builtin_amdgcn_update_dpp(v, v, CTRL, 0xF, 0xF, true);
    return __int_as_float(v);
}
template<int CTRL, int RMASK>
__device__ __forceinline__ unsigned dpp_mov_u32(unsigned x) {
    int v = __builtin_amdgcn_update_dpp((int)x, (int)x, CTRL, RMASK, 0xF, true);
    return (unsigned)v;
}
__device__ __forceinline__ unsigned umax2(unsigned a, unsigned b) {
    return a > b ? a : b;
}
__device__ __forceinline__ int imin2(int a, int b) { return a < b ? a : b; }

// ---------------- fused kernel: 64 blocks, one batch each -----------------
// wave 0  : in-register setup (f64, R12 semantics) + recur chain (R12 code)
// waves1-3: block-local X producer (bit-identical arithmetic to R12 gemm:
//           per-column dual-accumulator A(x,y)/B(z,w) over a0 — grouping by
//           20 cols does not change each column's accumulation order)
// Sync: LDS-only (same CU). Producer: threadfence_block (vmcnt drain) THEN
// prog[wv]=it+1. Consumer: poll min(prog) every 64 steps (needs rows<=t+67;
// prefetch depth 4). No agent-scope atomics -> no cross-XCD traffic, no L1
// invalidation (R13 failure modes). Waves sit on 4 distinct SIMDs -> chain
// issue port stays private (R8/m114). Producer never waits -> deadlock-free.
__global__ __launch_bounds__(256) void fused_kernel(
        const float* __restrict__ hs, const float* __restrict__ W_ih,
        const float* __restrict__ codebook, const float* __restrict__ qs_W,
        const float* __restrict__ qs_b, const float* __restrict__ b_ih,
        const float* __restrict__ b_hh, const float* __restrict__ W_hh,
        const int* __restrict__ inds, float* __restrict__ out_embs,
        char* __restrict__ ws) {
    __shared__ int prog[4];
    __shared__ double red[256];
    const int b = blockIdx.x;
    const int tid = threadIdx.x;
    const int wv = tid >> 6;
    float* X32 = (float*)(ws + OFF_X32);

    if (tid == 0) { prog[1] = 0; prog[2] = 0; prog[3] = 0; }
    __syncthreads();
    volatile int* vprog = prog;

    if (wv != 0) {
        // ---------------- producer: rows of this batch ----------------
        const int lane = tid & 63;
        for (int it = 0; it < 11; ++it) {
            int r = it * 192 + (wv - 1) * 64 + lane;
            if (r < TT) {
                const float* xr = hs + ((long)b * TT + r) * ADIM;
                float* op = X32 + ((long)b * TT + r) * NG;
#pragma unroll
                for (int pass = 0; pass < 2; ++pass) {
                    const int cbase = pass * 20;
                    float accA[20], accB[20];
#pragma unroll
                    for (int j = 0; j < 20; ++j) { accA[j] = 0.0f; accB[j] = 0.0f; }
                    for (int a0 = 0; a0 < ADIM; a0 += 4) {
                        float4 xv = *(const float4*)(xr + a0);
#pragma unroll
                        for (int j = 0; j < 20; ++j) {
                            float4 w4 = *(const float4*)(W_ih + (cbase + j) * ADIM + a0);
                            accA[j] = fmaf(w4.x, xv.x, accA[j]);
                            accA[j] = fmaf(w4.y, xv.y, accA[j]);
                            accB[j] = fmaf(w4.z, xv.z, accB[j]);
                            accB[j] = fmaf(w4.w, xv.w, accB[j]);
                        }
                    }
#pragma unroll
                    for (int j = 0; j < 20; ++j) op[cbase + j] = accA[j] + accB[j];
                }
            }
            __threadfence_block();           // drain stores to L2 (this wave)
            if ((tid & 63) == 0) vprog[wv] = it + 1;
        }
    } else {
        // ---------------- wave 0: setup (registers) + chain ----------------
        const int k = tid;
        const int j = k & 3;
        const int m = k >> 2;
        const bool valid = (k < NG);
        const int col = valid ? (j * 10 + m) : (NG - 1);
        const bool isg = (j == 2);

        // per-lane f64 setup (identical numerics to R12 setup_kernel)
        double M0 = 0, M1 = 0, M2 = 0, qbd = 0;
        for (int a = 0; a < ADIM; ++a) {
            double w = (double)W_ih[col * ADIM + a];
            M0 = fma(w, (double)qs_W[a * HD + 0], M0);
            M1 = fma(w, (double)qs_W[a * HD + 1], M1);
            M2 = fma(w, (double)qs_W[a * HD + 2], M2);
            qbd = fma(w, (double)qs_b[a], qbd);
        }
        double biasd = (double)b_ih[col] + (double)b_hh[col];
        float etab[NE];
#pragma unroll
        for (int i = 0; i < NE; ++i) {
            double e = biasd + qbd;
            e = fma((double)codebook[i * HD + 0], M0, e);
            e = fma((double)codebook[i * HD + 1], M1, e);
            e = fma((double)codebook[i * HD + 2], M2, e);
            etab[i] = (float)e;
        }
        float esel = (float)biasd;           // t==0: gate = x + bias (no qs)

        const float LOG2E = 1.44269504088896340736f;
        const float Lg   = isg ? (-2.0f * LOG2E) : (-LOG2E);
        const float amul = isg ? 2.0f : 1.0f;
        const float aadd = isg ? -1.0f : 0.0f;
        const float L2   = -2.0f * LOG2E;

        float whh[NE];
#pragma unroll
        for (int mm = 0; mm < NE; ++mm) whh[mm] = W_hh[col * NE + mm];

        const float* Xb = X32 + (long)b * TT * NG;

        const bool is_h = ((k & 3) == 0) && valid;
        const bool is_i = (k == NG);
        unsigned voff = is_h ? (unsigned)(OFF_H + ((unsigned)b * TT * NE + m) * 4u)
                      : is_i ? (unsigned)(OFF_IDX + (unsigned)b * TT * 4u)
                             : (unsigned)(OFF_DUMP + (unsigned)b * 256u);
        const unsigned vstep = is_h ? (unsigned)(NE * 4) : is_i ? 4u : 0u;
        const unsigned vmask = valid ? 0xFFFFFFFFu : 0u;   // keys on ALL 40 lanes

        // wait for chunk 0 (rows 0..191) before the prefetch prologue
        for (;;) {
            int mn = imin2(imin2(vprog[1], vprog[2]), vprog[3]);
            if (mn >= 1) break;
            __builtin_amdgcn_s_sleep(2);
        }
        asm volatile("" ::: "memory");       // no load hoisting above the spin

        float xs0 = Xb[0 * NG + col];
        float xs1 = Xb[1 * NG + col];
        float xs2 = Xb[2 * NG + col];
        float xs3 = Xb[3 * NG + col];

        float ha[NE];
#pragma unroll
        for (int mm = 0; mm < NE; ++mm) ha[mm] = 0.0f;
        float c = 0.0f;

        auto step = [&](float& xslot, int t) {
            float xg = xslot;
            xslot = Xb[(t + 4) * NG + col];

            float p0 = fmaf(ha[1], whh[1], ha[0] * whh[0]);
            float p1 = fmaf(ha[3], whh[3], ha[2] * whh[2]);
            float p2 = fmaf(ha[5], whh[5], ha[4] * whh[4]);
            float p3 = fmaf(ha[7], whh[7], ha[6] * whh[6]);
            float p4 = fmaf(ha[9], whh[9], ha[8] * whh[8]);
            float dotE = ((p0 + p1) + (p2 + p3)) + (p4 + esel);
            float g32 = xg + dotE;

            float e1 = fexp2(g32 * Lg);
            float r1 = frcp(1.0f + e1);
            float act = fmaf(amul, r1, aadd);

            // quad-redundant c,h REQUIRED by the argmax reduce (R3/R11 bug)
            float fiv = dpp_mov_f32<0x00>(act);
            float ffv = dpp_mov_f32<0x55>(act);
            float fgv = dpp_mov_f32<0xAA>(act);
            float fov = dpp_mov_f32<0xFF>(act);
            c = fmaf(ffv, c, fiv * fgv);

            float e2 = fexp2(fabsf(c) * L2);
            float r2 = frcp(1.0f + e2);
            float th = fmaf(2.0f, r2, -1.0f);
            float habs = fov * th;
            int hI = __float_as_int(habs) | (__float_as_int(c) & 0x80000000);

            int smsk = hI >> 31;
            unsigned key0 = ((unsigned)(hI ^ (smsk | (int)0x80000000))) & vmask;
            unsigned kr = umax2(key0, dpp_mov_u32<0x124, 0xF>(key0));  // ror:4
            kr = umax2(kr, dpp_mov_u32<0x128, 0xF>(kr));               // ror:8
            kr = umax2(kr, dpp_mov_u32<0x142, 0xA>(kr));               // bcast15
            kr = umax2(kr, dpp_mov_u32<0x143, 0xC>(kr));               // bcast31
            unsigned sMax = (unsigned)__builtin_amdgcn_readlane((int)kr, 32);
            unsigned long long ball = __ballot(key0 == sMax);
            int s_idx = ((int)__builtin_ctzll(ball)) >> 2;

            int val = is_h ? hI : s_idx;
            *(int*)(ws + voff) = val;
            voff += vstep;

#pragma unroll
            for (int mm = 0; mm < NE; ++mm)
                ha[mm] = __int_as_float(__builtin_amdgcn_readlane(hI, 4 * mm));

            float a0 = (s_idx & 1) ? etab[1] : etab[0];
            float a1 = (s_idx & 1) ? etab[3] : etab[2];
            float a2 = (s_idx & 1) ? etab[5] : etab[4];
            float a3 = (s_idx & 1) ? etab[7] : etab[6];
            float a4 = (s_idx & 1) ? etab[9] : etab[8];
            float b0 = (s_idx & 2) ? a1 : a0;
            float b1 = (s_idx & 2) ? a3 : a2;
            float c0 = (s_idx & 4) ? b1 : b0;
            esel = (s_idx & 8) ? a4 : c0;
        };

        for (int t = 0; t < TT; t += 4) {
            if ((t & 63) == 0) {
                int need = t + 68; if (need > TT) need = TT;
                for (;;) {
                    int mn = imin2(imin2(vprog[1], vprog[2]), vprog[3]);
                    if (mn * 192 >= need) break;
                    __builtin_amdgcn_s_sleep(2);
                }
                asm volatile("" ::: "memory");
            }
            step(xs0, t);
            step(xs1, t + 1);
            step(xs2, t + 2);
            step(xs3, t + 3);
        }
    }

    __syncthreads();   // drains chain stores; producers long done

    // ---------------- inline tail for batch b (all 256 threads) ------------
    const float* h_ws = (const float*)(ws + OFF_H);
    const int* idx_ws = (const int*)(ws + OFF_IDX);
    double psum = 0.0;
    for (int t = tid; t < TT; t += 256) {
        long i = (long)b * TT + t;
        int idx = idx_ws[i];
        out_embs[i * 3 + 0] = codebook[idx * 3 + 0];
        out_embs[i * 3 + 1] = codebook[idx * 3 + 1];
        out_embs[i * 3 + 2] = codebook[idx * 3 + 2];

        const float* hp = h_ws + i * NE;
        double hv[NE];
#pragma unroll
        for (int mm = 0; mm < NE; ++mm) hv[mm] = (double)hp[mm];
        double mx = hv[0];
#pragma unroll
        for (int mm = 1; mm < NE; ++mm) mx = fmax(mx, hv[mm]);
        double sdn = 0.0;
#pragma unroll
        for (int mm = 0; mm < NE; ++mm) sdn += exp(hv[mm] - mx);
        int ind = inds[i];
        psum += (double)hp[ind] - (mx + log(sdn));
    }
    red[tid] = psum;
    __syncthreads();
    for (int st = 128; st > 0; st >>= 1) {
        if (tid < st) red[tid] += red[tid + st];
        __syncthreads();
    }
    if (tid == 0) ((double*)(ws + OFF_PART))[b] = red[0];
}

// ---------------- final: sum 64 per-batch partials (deterministic) ---------
__global__ __launch_bounds__(64) void final_kernel(
        const double* __restrict__ partials, float* __restrict__ out_loss) {
    if (threadIdx.x == 0) {
        double s = 0.0;
        for (int i = 0; i < BB; ++i) s += partials[i];
        out_loss[0] = (float)(-s / (double)(BB * TT));
    }
}

extern "C" void kernel_launch(void* const* d_in, const int* in_sizes, int n_in,
                              void* d_out, int out_size, void* d_ws, size_t ws_size,
                              hipStream_t stream) {
    const float* hs       = (const float*)d_in[0];
    const int*   inds     = (const int*)d_in[1];
    const float* codebook = (const float*)d_in[2];
    const float* W_ih     = (const float*)d_in[3];
    const float* W_hh     = (const float*)d_in[4];
    const float* b_ih     = (const float*)d_in[5];
    const float* b_hh     = (const float*)d_in[6];
    const float* qs_W     = (const float*)d_in[7];
    const float* qs_b     = (const float*)d_in[8];
    float* out = (float*)d_out;

    char* ws = (char*)d_ws;
    double* part = (double*)(ws + OFF_PART);

    fused_kernel<<<BB, 256, 0, stream>>>(hs, W_ih, codebook, qs_W, qs_b,
                                         b_ih, b_hh, W_hh, inds, out, ws);
    final_kernel<<<1, 64, 0, stream>>>(part, out + (size_t)BB * TT * HD);
}

// Round 15
// 536.631 us; speedup vs baseline: 1.8266x; 1.8266x over previous
//
#include <hip/hip_runtime.h>
#include <math.h>

#define BB 64
#define TT 2048
#define ADIM 384
#define NE 10    // num_embeddings == LSTM hidden
#define NG 40    // 4*NE gates
#define HD 3     // hidden_dim (codebook width)

// ---------------- workspace layout (bytes) ----------------
#define OFF_X32   0ULL                        // BB*TT*NG*4 = 20971520 (+slack)
#define OFF_H     (41943040ULL + 126400ULL)   // BB*TT*NE*4 = 5242880
#define OFF_IDX   (OFF_H + 5242880ULL)        // BB*TT*4 = 524288
#define OFF_PART  (OFF_IDX + 524288ULL)       // 64*8 partials
#define OFF_DUMP  (OFF_PART + 4096ULL)        // per-block dump words (64*256B)

// ---------------- fast helpers ----------------
__device__ __forceinline__ float fexp2(float x) {   // HW 2^x, ~1 ulp
    float r;
    asm("v_exp_f32 %0, %1" : "=v"(r) : "v"(x));
    return r;
}
__device__ __forceinline__ float frcp(float d) {    // HW rcp, ~1 ulp
    float r;
    asm("v_rcp_f32 %0, %1" : "=v"(r) : "v"(d));
    return r;
}

template<int CTRL>
__device__ __forceinline__ float dpp_mov_f32(float x) {
    int v = __float_as_int(x);
    v = __builtin_amdgcn_update_dpp(v, v, CTRL, 0xF, 0xF, true);
    return __int_as_float(v);
}
template<int CTRL, int RMASK>
__device__ __forceinline__ unsigned dpp_mov_u32(unsigned x) {
    int v = __builtin_amdgcn_update_dpp((int)x, (int)x, CTRL, RMASK, 0xF, true);
    return (unsigned)v;
}
__device__ __forceinline__ unsigned umax2(unsigned a, unsigned b) {
    return a > b ? a : b;
}

// ---------------- X = hs @ W_ih.T  (f32, dual accumulator; R12 exact) ------
__global__ __launch_bounds__(256) void gemm_kernel(
        const float* __restrict__ hs, const float* __restrict__ W_ih,
        float* __restrict__ X32) {
    int lane = threadIdx.x & 63;
    int wv = threadIdx.x >> 6;
    int cb = __builtin_amdgcn_readfirstlane(wv * 10);   // wave-uniform col base
    long row = (long)blockIdx.x * 64 + lane;            // < 131072
    const float* xr = hs + row * ADIM;
    float accA[10], accB[10];
#pragma unroll
    for (int j = 0; j < 10; ++j) { accA[j] = 0.0f; accB[j] = 0.0f; }
    for (int a0 = 0; a0 < ADIM; a0 += 4) {
        float4 xv = *(const float4*)(xr + a0);
#pragma unroll
        for (int j = 0; j < 10; ++j) {
            float4 wv4 = *(const float4*)(W_ih + (cb + j) * ADIM + a0);
            accA[j] = fmaf(wv4.x, xv.x, accA[j]);
            accA[j] = fmaf(wv4.y, xv.y, accA[j]);
            accB[j] = fmaf(wv4.z, xv.z, accB[j]);
            accB[j] = fmaf(wv4.w, xv.w, accB[j]);
        }
    }
    float* op = X32 + row * NG + cb;
#pragma unroll
    for (int j = 0; j < 10; ++j) op[j] = accA[j] + accB[j];
}

// ---------------- recur + inline tail: 64 blocks x 256 threads -------------
// Wave 0: in-register f64 setup (R14-validated) + R12 chain (bit-identical).
// Waves 1-3 park at __syncthreads (no issue traffic — unlike R14's active
// producers, which saturated the CU's L1/TA and slowed the chain 2.5x).
// Then all 256 threads run the tail (embs gather + NLL partial) for batch b.
// QUAD layout: lane 4m+j = gate j of embedding m; quad-redundant c,h
// REQUIRED by the DPP argmax reduce (R3/R11 failure mode — keys must live
// in every mod-4 congruence class). 1 wave/SIMD for the chain (R8); all on
// VALU (R5); branchless stores (R8); exact u32-key argmax + ballot ties.
__global__ __launch_bounds__(256) void recur_tail_kernel(
        const float* __restrict__ W_ih, const float* __restrict__ codebook,
        const float* __restrict__ qs_W, const float* __restrict__ qs_b,
        const float* __restrict__ b_ih, const float* __restrict__ b_hh,
        const float* __restrict__ W_hh, const int* __restrict__ inds,
        float* __restrict__ out_embs, char* __restrict__ ws) {
    __shared__ double red[256];
    const int b = blockIdx.x;
    const int tid = threadIdx.x;

    if (tid < 64) {
        const int k = tid;
        const int j = k & 3;
        const int m = k >> 2;
        const bool valid = (k < NG);
        const int col = valid ? (j * 10 + m) : (NG - 1);
        const bool isg = (j == 2);

        // per-lane f64 setup (identical numerics to R12's setup_kernel)
        double M0 = 0, M1 = 0, M2 = 0, qbd = 0;
        for (int a = 0; a < ADIM; ++a) {
            double w = (double)W_ih[col * ADIM + a];
            M0 = fma(w, (double)qs_W[a * HD + 0], M0);
            M1 = fma(w, (double)qs_W[a * HD + 1], M1);
            M2 = fma(w, (double)qs_W[a * HD + 2], M2);
            qbd = fma(w, (double)qs_b[a], qbd);
        }
        double biasd = (double)b_ih[col] + (double)b_hh[col];
        float etab[NE];
#pragma unroll
        for (int i = 0; i < NE; ++i) {
            double e = biasd + qbd;          // t>0 esel includes bias + qb
            e = fma((double)codebook[i * HD + 0], M0, e);
            e = fma((double)codebook[i * HD + 1], M1, e);
            e = fma((double)codebook[i * HD + 2], M2, e);
            etab[i] = (float)e;
        }
        float esel = (float)biasd;           // t==0: gate = x + bias (no qs)

        const float LOG2E = 1.44269504088896340736f;
        const float Lg   = isg ? (-2.0f * LOG2E) : (-LOG2E);
        const float amul = isg ? 2.0f : 1.0f;
        const float aadd = isg ? -1.0f : 0.0f;
        const float L2   = -2.0f * LOG2E;

        float whh[NE];
#pragma unroll
        for (int mm = 0; mm < NE; ++mm) whh[mm] = W_hh[col * NE + mm];

        const float* Xb = (const float*)(ws + OFF_X32) + (long)b * TT * NG;

        const bool is_h = ((k & 3) == 0) && valid;
        const bool is_i = (k == NG);
        unsigned voff = is_h ? (unsigned)(OFF_H + ((unsigned)b * TT * NE + m) * 4u)
                      : is_i ? (unsigned)(OFF_IDX + (unsigned)b * TT * 4u)
                             : (unsigned)(OFF_DUMP + (unsigned)b * 256u);
        const unsigned vstep = is_h ? (unsigned)(NE * 4) : is_i ? 4u : 0u;
        const unsigned vmask = valid ? 0xFFFFFFFFu : 0u;   // keys on ALL 40 lanes

        // prefetch ring depth 4 (overrun reads stay inside allocated ws slack)
        float xs0 = Xb[0 * NG + col];
        float xs1 = Xb[1 * NG + col];
        float xs2 = Xb[2 * NG + col];
        float xs3 = Xb[3 * NG + col];

        float ha[NE];
#pragma unroll
        for (int mm = 0; mm < NE; ++mm) ha[mm] = 0.0f;
        float c = 0.0f;

        auto step = [&](float& xslot, int t) {
            float xg = xslot;
            xslot = Xb[(t + 4) * NG + col];

            float p0 = fmaf(ha[1], whh[1], ha[0] * whh[0]);
            float p1 = fmaf(ha[3], whh[3], ha[2] * whh[2]);
            float p2 = fmaf(ha[5], whh[5], ha[4] * whh[4]);
            float p3 = fmaf(ha[7], whh[7], ha[6] * whh[6]);
            float p4 = fmaf(ha[9], whh[9], ha[8] * whh[8]);
            float dotE = ((p0 + p1) + (p2 + p3)) + (p4 + esel);
            float g32 = xg + dotE;

            float e1 = fexp2(g32 * Lg);
            float r1 = frcp(1.0f + e1);
            float act = fmaf(amul, r1, aadd);

            // quad-redundant c,h REQUIRED by the argmax reduce (R3/R11 bug)
            float fiv = dpp_mov_f32<0x00>(act);
            float ffv = dpp_mov_f32<0x55>(act);
            float fgv = dpp_mov_f32<0xAA>(act);
            float fov = dpp_mov_f32<0xFF>(act);
            c = fmaf(ffv, c, fiv * fgv);

            float e2 = fexp2(fabsf(c) * L2);
            float r2 = frcp(1.0f + e2);
            float th = fmaf(2.0f, r2, -1.0f);
            float habs = fov * th;
            int hI = __float_as_int(habs) | (__float_as_int(c) & 0x80000000);

            int smsk = hI >> 31;
            unsigned key0 = ((unsigned)(hI ^ (smsk | (int)0x80000000))) & vmask;
            unsigned kr = umax2(key0, dpp_mov_u32<0x124, 0xF>(key0));  // ror:4
            kr = umax2(kr, dpp_mov_u32<0x128, 0xF>(kr));               // ror:8
            kr = umax2(kr, dpp_mov_u32<0x142, 0xA>(kr));               // bcast15
            kr = umax2(kr, dpp_mov_u32<0x143, 0xC>(kr));               // bcast31
            unsigned sMax = (unsigned)__builtin_amdgcn_readlane((int)kr, 32);
            unsigned long long ball = __ballot(key0 == sMax);
            int s_idx = ((int)__builtin_ctzll(ball)) >> 2;

            int val = is_h ? hI : s_idx;
            *(int*)(ws + voff) = val;
            voff += vstep;

#pragma unroll
            for (int mm = 0; mm < NE; ++mm)
                ha[mm] = __int_as_float(__builtin_amdgcn_readlane(hI, 4 * mm));

            float a0 = (s_idx & 1) ? etab[1] : etab[0];
            float a1 = (s_idx & 1) ? etab[3] : etab[2];
            float a2 = (s_idx & 1) ? etab[5] : etab[4];
            float a3 = (s_idx & 1) ? etab[7] : etab[6];
            float a4 = (s_idx & 1) ? etab[9] : etab[8];
            float b0 = (s_idx & 2) ? a1 : a0;
            float b1 = (s_idx & 2) ? a3 : a2;
            float c0 = (s_idx & 4) ? b1 : b0;
            esel = (s_idx & 8) ? a4 : c0;
        };

        for (int t = 0; t < TT; t += 4) {
            step(xs0, t);
            step(xs1, t + 1);
            step(xs2, t + 2);
            step(xs3, t + 3);
        }
    }

    __syncthreads();   // waves 1-3 parked here during the chain (no issue)

    // ---------------- inline tail for batch b (all 256 threads) ------------
    const float* h_ws = (const float*)(ws + OFF_H);
    const int* idx_ws = (const int*)(ws + OFF_IDX);
    double psum = 0.0;
    for (int t = tid; t < TT; t += 256) {
        long i = (long)b * TT + t;
        int idx = idx_ws[i];
        out_embs[i * 3 + 0] = codebook[idx * 3 + 0];
        out_embs[i * 3 + 1] = codebook[idx * 3 + 1];
        out_embs[i * 3 + 2] = codebook[idx * 3 + 2];

        const float* hp = h_ws + i * NE;
        double hv[NE];
#pragma unroll
        for (int mm = 0; mm < NE; ++mm) hv[mm] = (double)hp[mm];
        double mx = hv[0];
#pragma unroll
        for (int mm = 1; mm < NE; ++mm) mx = fmax(mx, hv[mm]);
        double sdn = 0.0;
#pragma unroll
        for (int mm = 0; mm < NE; ++mm) sdn += exp(hv[mm] - mx);
        int ind = inds[i];
        psum += (double)hp[ind] - (mx + log(sdn));
    }
    red[tid] = psum;
    __syncthreads();
    for (int st = 128; st > 0; st >>= 1) {
        if (tid < st) red[tid] += red[tid + st];
        __syncthreads();
    }
    if (tid == 0) ((double*)(ws + OFF_PART))[b] = red[0];
}

// ---------------- final: sum 64 per-batch partials (deterministic) ---------
__global__ __launch_bounds__(64) void final_kernel(
        const double* __restrict__ partials, float* __restrict__ out_loss) {
    if (threadIdx.x == 0) {
        double s = 0.0;
        for (int i = 0; i < BB; ++i) s += partials[i];
        out_loss[0] = (float)(-s / (double)(BB * TT));
    }
}

extern "C" void kernel_launch(void* const* d_in, const int* in_sizes, int n_in,
                              void* d_out, int out_size, void* d_ws, size_t ws_size,
                              hipStream_t stream) {
    const float* hs       = (const float*)d_in[0];
    const int*   inds     = (const int*)d_in[1];
    const float* codebook = (const float*)d_in[2];
    const float* W_ih     = (const float*)d_in[3];
    const float* W_hh     = (const float*)d_in[4];
    const float* b_ih     = (const float*)d_in[5];
    const float* b_hh     = (const float*)d_in[6];
    const float* qs_W     = (const float*)d_in[7];
    const float* qs_b     = (const float*)d_in[8];
    float* out = (float*)d_out;

    char* ws = (char*)d_ws;
    float*  X32  = (float*)(ws + OFF_X32);
    double* part = (double*)(ws + OFF_PART);

    gemm_kernel<<<2048, 256, 0, stream>>>(hs, W_ih, X32);
    recur_tail_kernel<<<BB, 256, 0, stream>>>(W_ih, codebook, qs_W, qs_b,
                                              b_ih, b_hh, W_hh, inds, out, ws);
    final_kernel<<<1, 64, 0, stream>>>(part, out + (size_t)BB * TT * HD);
}